// Round 11
// baseline (247.310 us; speedup 1.0000x reference)
//
#include <hip/hip_runtime.h>
#include <hip/hip_bf16.h>

#define DEVI __device__ __forceinline__

constexpr int Bc = 2, Cc = 64, Tc = 4, Hc = 64, Wc = 64, OFFc = 54, KVc = 27;
constexpr int HW  = Hc * Wc;     // 4096
constexpr int THW = Tc * HW;     // 16384

typedef __attribute__((ext_vector_type(8))) short bf16x8;
typedef __attribute__((ext_vector_type(4))) float f32x4;

DEVI short f2bf(float f) {
    __hip_bfloat16 h = __float2bfloat16(f);
    return *reinterpret_cast<short*>(&h);
}
DEVI float bf2f(short s) {
    unsigned u = ((unsigned)(unsigned short)s) << 16;
    float f; __builtin_memcpy(&f, &u, 4); return f;
}

// ------- weights -> K-major MFMA A layout -------
__global__ __launch_bounds__(256) void w_prep(const float* __restrict__ w,
                                              __hip_bfloat16* __restrict__ wAk, int ovalid) {
    int i = blockIdx.x * 256 + threadIdx.x;   // 216*512 = 110592
    if (i >= 216 * 512) return;
    int u = i >> 9, r = i & 511;
    int mf = u & 3, ch = (u >> 2) & 1, tap = u >> 3;
    int o = mf * 16 + (r >> 5), c = ch * 32 + (r & 31);
    float v = (o < ovalid) ? w[(o * Cc + c) * KVc + tap] : 0.f;
    wAk[i] = __float2bfloat16(v);
}

// ------- cast + transpose to channel-last bf16 -------
__global__ __launch_bounds__(256) void cast_cl(const float* __restrict__ x,
                                               __hip_bfloat16* __restrict__ xcl) {
    __shared__ float s[64][65];
    int tid = threadIdx.x;
    int bi  = blockIdx.x;
    int h = bi & 63, t = (bi >> 6) & 3, b = bi >> 8;

    const float* xp = x + (size_t)b * Cc * THW + t * HW + h * 64;
    int w0 = tid & 63, c0 = tid >> 6;
    #pragma unroll
    for (int i = 0; i < 16; ++i) {
        int c = c0 + i * 4;
        s[c][w0] = xp[(size_t)c * THW + w0];
    }
    __syncthreads();

    __hip_bfloat16* dst = xcl + (((size_t)b * Tc + t) * HW + (size_t)h * 64) * 64;
    #pragma unroll
    for (int r = 0; r < 2; ++r) {
        int j  = tid + r * 256;
        int w  = j >> 3;
        int c8 = j & 7;
        bf16x8 v;
        #pragma unroll
        for (int jj = 0; jj < 8; ++jj)
            v[jj] = f2bf(s[c8 * 8 + jj][w]);
        *reinterpret_cast<bf16x8*>(dst + w * 64 + c8 * 8) = v;
    }
}

// ================= fused offset-conv + deformable-conv, LDS-staged, pipelined =================
// block = (b,t,h) full row, 512 thr = 8 waves = nf(4) x chh(2).
// XCD pairing: each XCD gets one light (t in {0,3}) + one heavy (t in {1,2})
// half-plane job -> balanced taps AND ~1MB L2 footprint per XCD.
// Per kt: tile rows [h-2,h+2] staged via register-prefetch (T14); both passes'
// inner loops are depth-2 issue/consume pipelines where issue() holds ALL
// vector loads (LDS gathers + af weight fragments) and consume() is VALU+MFMA.
template <bool L2>
__global__ __launch_bounds__(512, 4) void fused_deform(
    const __hip_bfloat16* __restrict__ src, const __hip_bfloat16* __restrict__ owAk,
    const float* __restrict__ obias, const __hip_bfloat16* __restrict__ wAk,
    const float* __restrict__ xres, float* __restrict__ outf,
    __hip_bfloat16* __restrict__ ycl)
{
    __shared__ __align__(16) char s_mem[40960 + 14256];
    short* s_tile = (short*)s_mem;                 // [5][64 w][64 c] bf16, swizzled
    float* s_off  = (float*)(s_mem + 40960);       // [54][66]
    float* s_red  = (float*)s_mem;                 // aliased after pass B: [64][68]

    int tid = threadIdx.x;
    int wv = tid >> 6, lane = tid & 63, l15 = lane & 15, l4 = lane >> 4;
    int nf = wv & 3, chh = wv >> 2;

    // ---- light/heavy paired XCD decode ----
    int bi = blockIdx.x;
    int x8 = bi & 7, u = bi >> 3;
    int sel = u & 1, hloc = u >> 1;            // hloc 0..31
    int b = x8 >> 2, pairbit = (x8 >> 1) & 1, hhalf = x8 & 1;
    int t = sel ? (pairbit ? 3 : 1) : (pairbit ? 2 : 0);
    int h = hhalf * 32 + hloc;

    int p = nf * 16 + l15;               // position (MFMA N index)
    int cbase = chh * 32 + l4 * 8;       // channel slice (MFMA K slice)
    int ktlo = (t == 0) ? 1 : 0, kthi = (t == 3) ? 2 : 3;

    for (int i = tid; i < OFFc * 66; i += 512) s_off[i] = obias[i / 66];

    const __hip_bfloat16* xb = src + ((size_t)b << 20);
    int wst = tid >> 3, sst = tid & 7;   // staging lane coords

    auto stage_load = [&](int kt, bf16x8 (&reg)[5]) {
        int tt = t + kt - 1;
        const __hip_bfloat16* xt = xb + ((size_t)tt << 18);
        #pragma unroll
        for (int r = 0; r < 5; ++r) {
            int hh = h - 2 + r;
            bf16x8 v = {0, 0, 0, 0, 0, 0, 0, 0};
            if ((unsigned)hh < 64u)
                v = *reinterpret_cast<const bf16x8*>(xt + ((hh * 64 + wst) << 6) + sst * 8);
            reg[r] = v;
        }
    };
    auto stage_write = [&](bf16x8 (&reg)[5]) {
        #pragma unroll
        for (int r = 0; r < 5; ++r) {
            int byte = (r * 8192 + wst * 128 + sst * 16) ^ ((wst & 7) << 4);
            *reinterpret_cast<bf16x8*>((char*)s_tile + byte) = reg[r];
        }
    };
    auto ldread = [&](int sl, int w) -> bf16x8 {
        int byte = (sl * 8192 + w * 128 + cbase * 2) ^ ((w & 7) << 4);
        return *reinterpret_cast<const bf16x8*>((const char*)s_tile + byte);
    };

    // ================= pass A: offset conv =================
    {
        f32x4 cacc[4];
        #pragma unroll
        for (int mf = 0; mf < 4; ++mf) cacc[mf] = (f32x4){0.f, 0.f, 0.f, 0.f};

        auto issueA = [&](int kt, int rr, bf16x8 &bv, bf16x8 (&af)[4]) {
            int kh = rr / 3, kw = rr % 3, tap = kt * 9 + rr;
            int ws = p + kw - 1;
            int wsc = min(max(ws, 0), 63);
            bv = ldread(kh + 1, wsc);
            if ((unsigned)ws >= 64u) bv = (bf16x8){0, 0, 0, 0, 0, 0, 0, 0};
            const __hip_bfloat16* ab = owAk + ((tap * 2 + chh) << 11) + (l15 << 5) + (l4 << 3);
            #pragma unroll
            for (int mf = 0; mf < 4; ++mf)
                af[mf] = *reinterpret_cast<const bf16x8*>(ab + (mf << 9));
        };
        auto consumeA = [&](bf16x8 &bv, bf16x8 (&af)[4]) {
            #pragma unroll
            for (int mf = 0; mf < 4; ++mf)
                cacc[mf] = __builtin_amdgcn_mfma_f32_16x16x32_bf16(af[mf], bv, cacc[mf], 0, 0, 0);
        };

        bf16x8 streg[5];
        stage_load(ktlo, streg);
        for (int kt = ktlo; kt < kthi; ++kt) {
            __syncthreads();
            stage_write(streg);
            __syncthreads();
            if (kt + 1 < kthi) stage_load(kt + 1, streg);

            bf16x8 bvA, bvB, afA[4], afB[4];
            issueA(kt, 0, bvA, afA);
            #pragma unroll
            for (int rr = 0; rr < 8; rr += 2) {
                issueA(kt, rr + 1, bvB, afB);
                consumeA(bvA, afA);
                if (rr + 2 < 9) issueA(kt, rr + 2, bvA, afA);
                consumeA(bvB, afB);
            }
            consumeA(bvA, afA);   // rr = 8
        }
        #pragma unroll
        for (int mf = 0; mf < 4; ++mf)
            #pragma unroll
            for (int jj = 0; jj < 4; ++jj) {
                int o = mf * 16 + l4 * 4 + jj;
                if (o < OFFc) atomicAdd(&s_off[o * 66 + p], cacc[mf][jj]);
            }
    }

    // ================= pass B: deformable conv =================
    f32x4 dacc[4];
    #pragma unroll
    for (int mf = 0; mf < 4; ++mf) dacc[mf] = (f32x4){0.f, 0.f, 0.f, 0.f};

    {
        auto issueB = [&](int kt, int rr, bf16x8 (&g)[4], bf16x8 (&af)[4], float (&cf)[4]) {
            int kh = rr / 3, kw = rr % 3, tap = kt * 9 + rr;
            int tt = t + kt - 1;
            const __hip_bfloat16* xt = xb + ((size_t)tt << 18);
            float dh = s_off[(tap * 2 + 0) * 66 + p];
            float dw = s_off[(tap * 2 + 1) * 66 + p];
            float hs  = (float)(h + kh - 1) + dh;
            float wsf = (float)(p + kw - 1) + dw;
            float fh = floorf(hs), fw = floorf(wsf);
            int h0 = (int)fh, w0 = (int)fw;
            float lh = hs - fh, lw = wsf - fw;
            float q0 = (1.f - lw) * (((unsigned)w0 < 64u) ? 1.f : 0.f);
            float q1 = lw         * (((unsigned)(w0 + 1) < 64u) ? 1.f : 0.f);
            int wc0 = min(max(w0, 0), 63), wc1 = min(max(w0 + 1, 0), 63);
            int r0 = h0 - (h - 2);
            int r0c = min(max(r0, 0), 3);
            // always-issued LDS reads (discarded if fallback)
            g[0] = ldread(r0c, wc0);     g[1] = ldread(r0c, wc1);
            g[2] = ldread(r0c + 1, wc0); g[3] = ldread(r0c + 1, wc1);
            bool bad = (r0 < 0) | (r0 > 3);
            if (__any((int)bad)) {
                // exact global fallback (|dh| >= 1; ~never taken)
                float u0 = (1.f - lh) * (((unsigned)h0 < 64u) ? 1.f : 0.f);
                float u1 = lh         * (((unsigned)(h0 + 1) < 64u) ? 1.f : 0.f);
                cf[0] = u0 * q0; cf[1] = u0 * q1; cf[2] = u1 * q0; cf[3] = u1 * q1;
                int hc0 = min(max(h0, 0), 63), hc1 = min(max(h0 + 1, 0), 63);
                g[0] = *reinterpret_cast<const bf16x8*>(xt + ((hc0 * 64 + wc0) << 6) + cbase);
                g[1] = *reinterpret_cast<const bf16x8*>(xt + ((hc0 * 64 + wc1) << 6) + cbase);
                g[2] = *reinterpret_cast<const bf16x8*>(xt + ((hc1 * 64 + wc0) << 6) + cbase);
                g[3] = *reinterpret_cast<const bf16x8*>(xt + ((hc1 * 64 + wc1) << 6) + cbase);
            } else {
                cf[0] = (1.f - lh) * q0; cf[1] = (1.f - lh) * q1;
                cf[2] = lh * q0;         cf[3] = lh * q1;
            }
            const __hip_bfloat16* ab = wAk + ((tap * 2 + chh) << 11) + (l15 << 5) + (l4 << 3);
            #pragma unroll
            for (int mf = 0; mf < 4; ++mf)
                af[mf] = *reinterpret_cast<const bf16x8*>(ab + (mf << 9));
        };
        auto consumeB = [&](bf16x8 (&g)[4], bf16x8 (&af)[4], float (&cf)[4]) {
            bf16x8 bfrag;
            #pragma unroll
            for (int jj = 0; jj < 8; ++jj) {
                float s = cf[0] * bf2f(g[0][jj]) + cf[1] * bf2f(g[1][jj])
                        + cf[2] * bf2f(g[2][jj]) + cf[3] * bf2f(g[3][jj]);
                bfrag[jj] = f2bf(s);
            }
            #pragma unroll
            for (int mf = 0; mf < 4; ++mf)
                dacc[mf] = __builtin_amdgcn_mfma_f32_16x16x32_bf16(af[mf], bfrag, dacc[mf], 0, 0, 0);
        };

        bf16x8 streg[5];
        stage_load(ktlo, streg);
        for (int kt = ktlo; kt < kthi; ++kt) {
            __syncthreads();          // also guards s_off completeness on first iter
            stage_write(streg);
            __syncthreads();
            if (kt + 1 < kthi) stage_load(kt + 1, streg);

            bf16x8 gA[4], gB[4], afA[4], afB[4];
            float cA[4], cB[4];
            issueB(kt, 0, gA, afA, cA);
            #pragma unroll
            for (int rr = 0; rr < 8; rr += 2) {
                issueB(kt, rr + 1, gB, afB, cB);
                consumeB(gA, afA, cA);
                if (rr + 2 < 9) issueB(kt, rr + 2, gA, afA, cA);
                consumeB(gB, afB, cB);
            }
            consumeB(gA, afA, cA);    // rr = 8
        }
    }

    // ---- reduce: s_red aliased onto tile ----
    __syncthreads();
    for (int i = tid; i < 64 * 68; i += 512) s_red[i] = 0.f;
    __syncthreads();
    #pragma unroll
    for (int mf = 0; mf < 4; ++mf)
        #pragma unroll
        for (int jj = 0; jj < 4; ++jj) {
            int o = mf * 16 + l4 * 4 + jj;
            atomicAdd(&s_red[p * 68 + o], dacc[mf][jj]);
        }
    __syncthreads();

    // ---- fused epilogue ----
    if (!L2) {
        int pp = tid >> 3, o8 = (tid & 7) << 3;
        __hip_bfloat16* dst = ycl + ((((size_t)b * Tc + t) * HW + h * 64 + pp) << 6) + o8;
        bf16x8 o8v;
        #pragma unroll
        for (int jj = 0; jj < 8; ++jj) {
            float v = s_red[pp * 68 + o8 + jj];
            v = v >= 0.f ? v : 0.1f * v;
            o8v[jj] = f2bf(v);
        }
        *reinterpret_cast<bf16x8*>(dst) = o8v;
    } else {
        int o = tid >> 3, pg = (tid & 7) << 3;
        size_t base = ((size_t)(b * Cc + o) * Tc + t) * HW + h * 64 + pg;
        #pragma unroll
        for (int q = 0; q < 2; ++q) {
            f32x4 r, xv = *reinterpret_cast<const f32x4*>(xres + base + q * 4);
            #pragma unroll
            for (int jj = 0; jj < 4; ++jj) r[jj] = s_red[(pg + q * 4 + jj) * 68 + o] + xv[jj];
            *reinterpret_cast<f32x4*>(outf + base + q * 4) = r;
        }
    }
}

extern "C" void kernel_launch(void* const* d_in, const int* in_sizes, int n_in,
                              void* d_out, int out_size, void* d_ws, size_t ws_size,
                              hipStream_t stream)
{
    const float* x   = (const float*)d_in[0];
    const float* w0  = (const float*)d_in[1];
    const float* ow0 = (const float*)d_in[2];
    const float* ob0 = (const float*)d_in[3];
    const float* w1  = (const float*)d_in[4];
    const float* ow1 = (const float*)d_in[5];
    const float* ob1 = (const float*)d_in[6];
    float* out = (float*)d_out;

    __hip_bfloat16* xcl  = (__hip_bfloat16*)d_ws;
    __hip_bfloat16* ycl  = xcl  + (size_t)Bc * THW * 64;
    __hip_bfloat16* owA0 = ycl  + (size_t)Bc * THW * 64;
    __hip_bfloat16* owA1 = owA0 + (size_t)216 * 512;
    __hip_bfloat16* wA0  = owA1 + (size_t)216 * 512;
    __hip_bfloat16* wA1  = wA0  + (size_t)216 * 512;

    w_prep<<<432, 256, 0, stream>>>(ow0, owA0, OFFc);
    w_prep<<<432, 256, 0, stream>>>(ow1, owA1, OFFc);
    w_prep<<<432, 256, 0, stream>>>(w0,  wA0,  Cc);
    w_prep<<<432, 256, 0, stream>>>(w1,  wA1,  Cc);
    cast_cl<<<512, 256, 0, stream>>>(x, xcl);

    fused_deform<false><<<512, 512, 0, stream>>>(xcl, owA0, ob0, wA0, nullptr, nullptr, ycl);
    fused_deform<true><<<512, 512, 0, stream>>>(ycl, owA1, ob1, wA1, x, out, nullptr);
}